// Round 7
// baseline (1425.933 us; speedup 1.0000x reference)
//
#include <hip/hip_runtime.h>
#include <math.h>

#define NS   512   // states
#define NO   1024  // observations
#define NB   64    // batch
#define TMAX 512

// Per-thread A: 4 states x 16 chunks (uint4 = 8 fp16 k-values).
// m 0..7  -> AGPR  (32 uint4 = 128 AGPR words)
// m 8..11 -> LDS   (16 uint4 -> 128 KB)
// m 12..15-> streamed from L2 every step (16 uint4 -> 128 KB/CU/step)
#define MAGP 8
#define MLDS 4
#define MSTR 4

typedef _Float16 h2v __attribute__((ext_vector_type(2)));

__device__ inline float wave_red_sum(float x) {
#pragma unroll
  for (int o = 32; o; o >>= 1) x += __shfl_xor(x, o, 64);
  return x;
}
__device__ inline float wave_red_max(float x) {
#pragma unroll
  for (int o = 32; o; o >>= 1) x = fmaxf(x, __shfl_xor(x, o, 64));
  return x;
}

__device__ inline float dot2u(unsigned int a, unsigned int b, float c) {
#if __has_builtin(__builtin_amdgcn_fdot2)
  return __builtin_amdgcn_fdot2(__builtin_bit_cast(h2v, a),
                                __builtin_bit_cast(h2v, b), c, false);
#else
  h2v av = __builtin_bit_cast(h2v, a), bv = __builtin_bit_cast(h2v, b);
  return c + (float)av.x * (float)bv.x + (float)av.y * (float)bv.y;
#endif
}

#define AGWRITE(dst, src) \
  asm volatile("v_accvgpr_write_b32 %0, %1" : "=a"(dst) : "v"(src))
#define AGREAD(dst, src) \
  asm volatile("v_accvgpr_read_b32 %0, %1" : "=v"(dst) : "a"(src))

// P1: pi softmax -> pi_sm[512]
__global__ void k_pi(const float* __restrict__ pi, float* __restrict__ pi_sm) {
  __shared__ float red[8];
  int tid = threadIdx.x;
  float v = pi[tid];
  float m = wave_red_max(v);
  if ((tid & 63) == 0) red[tid >> 6] = m;
  __syncthreads();
  m = fmaxf(fmaxf(fmaxf(red[0], red[1]), fmaxf(red[2], red[3])),
            fmaxf(fmaxf(red[4], red[5]), fmaxf(red[6], red[7])));
  float e = __expf(v - m);
  float s = wave_red_sum(e);
  __syncthreads();
  if ((tid & 63) == 0) red[tid >> 6] = s;
  __syncthreads();
  s = red[0] + red[1] + red[2] + red[3] + red[4] + red[5] + red[6] + red[7];
  pi_sm[tid] = e / s;
}

// P2: column logsumexp of A (axis 0). One block (256 thr) per column. grid 512.
__global__ void k_colLse(const float* __restrict__ A, float* __restrict__ lseA) {
  __shared__ float redm[4];
  __shared__ float reds[4];
  int k = blockIdx.x, tid = threadIdx.x;
  float a0 = A[tid * NS + k], a1 = A[(tid + 256) * NS + k];
  float m = wave_red_max(fmaxf(a0, a1));
  if ((tid & 63) == 0) redm[tid >> 6] = m;
  __syncthreads();
  m = fmaxf(fmaxf(redm[0], redm[1]), fmaxf(redm[2], redm[3]));
  float s = __expf(a0 - m) + __expf(a1 - m);
  s = wave_red_sum(s);
  if ((tid & 63) == 0) reds[tid >> 6] = s;
  __syncthreads();
  s = reds[0] + reds[1] + reds[2] + reds[3];
  if (tid == 0) lseA[k] = m + __logf(s);
}

// P3: row logsumexp of E (axis 1). One block per row. grid 512 x 256.
__global__ void k_rowLseE(const float* __restrict__ E, float* __restrict__ lseE) {
  __shared__ float red[4];
  int i = blockIdx.x, tid = threadIdx.x;
  const float* row = E + i * NO;
  float a0 = row[tid], a1 = row[tid + 256], a2 = row[tid + 512], a3 = row[tid + 768];
  float m = fmaxf(fmaxf(a0, a1), fmaxf(a2, a3));
  m = wave_red_max(m);
  if ((tid & 63) == 0) red[tid >> 6] = m;
  __syncthreads();
  m = fmaxf(fmaxf(red[0], red[1]), fmaxf(red[2], red[3]));
  float s = __expf(a0 - m) + __expf(a1 - m) + __expf(a2 - m) + __expf(a3 - m);
  s = wave_red_sum(s);
  __syncthreads();
  if ((tid & 63) == 0) red[tid >> 6] = s;
  __syncthreads();
  s = red[0] + red[1] + red[2] + red[3];
  if (tid == 0) lseE[i] = m + __logf(s);
}

// P4: pack A_exp = exp(A - lseA[col]) fp16 for the k-split layout.
// k_fwd thread t (w=t>>6, l=t&63, kk=w&3, rr=w>>2), chunk c=r*16+m:
//   uint4 Apk[c*512 + t] holds state i = 256rr + 64r + l,
//   k = 128kk + 8m + 2h + {0,1} in word h.
// Word index u = (c*512 + t)*4 + h. grid 256 x 512.
__global__ void k_pack(const float* __restrict__ A, const float* __restrict__ lseA,
                       unsigned int* __restrict__ W) {
  int u = blockIdx.x * 512 + threadIdx.x;   // [0, 131072)
  int h = u & 3;
  int ct = u >> 2;
  int t = ct & 511;
  int c = ct >> 9;
  int m = c & 15;
  int r = c >> 4;
  int w = t >> 6, l = t & 63;
  int kk = w & 3, rr = w >> 2;
  int i = 256 * rr + 64 * r + l;
  int k0 = 128 * kk + 8 * m + 2 * h;
  float e0 = __expf(A[i * NS + k0]     - lseA[k0]);
  float e1 = __expf(A[i * NS + k0 + 1] - lseA[k0 + 1]);
  h2v p;
  p.x = (_Float16)e0;
  p.y = (_Float16)e1;
  W[u] = __builtin_bit_cast(unsigned int, p);
}

// Main forward: one block (512 thr, 8 waves) per batch.
// Wave w = (kk=w&3: k-slice [128kk,128kk+128), rr=w>>2: states [256rr,+256)).
// Lane l: states {256rr + 64r + l, r=0..3}. u-slice per wave = 64 words,
// loaded with ONE ds_read_b32 and broadcast by v_readlane (VALU, off the
// LDS pipe). A split: 32 uint4 AGPR + 16 uint4 LDS + 16 uint4 L2-stream.
// VGPR+AGPR ~ 238 <= 256 -> 2 waves/SIMD.
// Deferred pow2 rescale (absmax 0.0 in r3/r4/r5).
__global__ __launch_bounds__(512)
__attribute__((amdgpu_waves_per_eu(2)))
void k_fwd(
    const float* __restrict__ E, const int* __restrict__ x,
    const int* __restrict__ Tlen, const float* __restrict__ pi_sm,
    const float* __restrict__ lseE, const uint4* __restrict__ Apk,
    float* __restrict__ out) {
  __shared__ uint4 Alds[16 * 512];              // 128 KB
  __shared__ float Pf[4 * 512];                 // 8 KB partials P[kk][i]
  __shared__ unsigned int ubuf[2][256];         // 2 KB ping-pong packed u
  __shared__ int xrow[TMAX];                    // 2 KB
  __shared__ __align__(16) float red[2][8];     // ping-pong sigma partials
  int b = blockIdx.x, tid = threadIdx.x;
  int w = tid >> 6, l = tid & 63;
  int kk = w & 3;

  // Prologue: A chunks m 0..7 -> AGPRs, m 8..11 -> LDS.
  uint4 aag[4][MAGP];
#pragma unroll
  for (int r = 0; r < 4; r++) {
#pragma unroll
    for (int m = 0; m < MAGP; m++) {
      uint4 tmp = Apk[(r * 16 + m) * 512 + tid];
      AGWRITE(aag[r][m].x, tmp.x);
      AGWRITE(aag[r][m].y, tmp.y);
      AGWRITE(aag[r][m].z, tmp.z);
      AGWRITE(aag[r][m].w, tmp.w);
    }
  }
#pragma unroll
  for (int r = 0; r < 4; r++)
#pragma unroll
    for (int m = 0; m < MLDS; m++)
      Alds[(r * 4 + m) * 512 + tid] = Apk[(r * 16 + 8 + m) * 512 + tid];

  for (int j = tid; j < TMAX; j += 512) xrow[j] = x[b * TMAX + j];

  float pi_i  = pi_sm[tid];
  float lse_i = lseE[tid];
  const float* Erow = E + tid * NO;
  int Tb = Tlen[b];
  float c = 0.f;        // log2-domain accumulator
  float Dlog = 0.f;     // log2 d_{t-1}
  int gexp_prev = 19;
  int cur = 0;
  __syncthreads();

  for (int t = 0; t < Tb; t++) {
    float epre = Erow[xrow[t]];     // gather early; hides under dot
    if (t) {
      int tido = tid;
      asm volatile("" : "+v"(tido));   // opaque index: stream loads can't hoist
      // issue the 16 streamed chunks (from L2) up front
      uint4 sbuf[4][MSTR];
#pragma unroll
      for (int r = 0; r < 4; r++)
#pragma unroll
        for (int m = 0; m < MSTR; m++)
          sbuf[r][m] = Apk[(r * 16 + 12 + m) * 512 + tido];

      int up = (int)ubuf[cur][(kk << 6) + l];   // wave's 64-word u slice
      float a0 = 0.f, a1 = 0.f, a2 = 0.f, a3 = 0.f;

#pragma unroll
      for (int m = 0; m < MAGP; m++) {          // AGPR chunks
        unsigned int s0 = (unsigned int)__builtin_amdgcn_readlane(up, 4 * m + 0);
        unsigned int s1 = (unsigned int)__builtin_amdgcn_readlane(up, 4 * m + 1);
        unsigned int s2 = (unsigned int)__builtin_amdgcn_readlane(up, 4 * m + 2);
        unsigned int s3 = (unsigned int)__builtin_amdgcn_readlane(up, 4 * m + 3);
        uint4 v0, v1, v2, v3;
        AGREAD(v0.x, aag[0][m].x); AGREAD(v0.y, aag[0][m].y);
        AGREAD(v0.z, aag[0][m].z); AGREAD(v0.w, aag[0][m].w);
        AGREAD(v1.x, aag[1][m].x); AGREAD(v1.y, aag[1][m].y);
        AGREAD(v1.z, aag[1][m].z); AGREAD(v1.w, aag[1][m].w);
        AGREAD(v2.x, aag[2][m].x); AGREAD(v2.y, aag[2][m].y);
        AGREAD(v2.z, aag[2][m].z); AGREAD(v2.w, aag[2][m].w);
        AGREAD(v3.x, aag[3][m].x); AGREAD(v3.y, aag[3][m].y);
        AGREAD(v3.z, aag[3][m].z); AGREAD(v3.w, aag[3][m].w);
        a0 = dot2u(v0.x, s0, a0); a0 = dot2u(v0.y, s1, a0);
        a0 = dot2u(v0.z, s2, a0); a0 = dot2u(v0.w, s3, a0);
        a1 = dot2u(v1.x, s0, a1); a1 = dot2u(v1.y, s1, a1);
        a1 = dot2u(v1.z, s2, a1); a1 = dot2u(v1.w, s3, a1);
        a2 = dot2u(v2.x, s0, a2); a2 = dot2u(v2.y, s1, a2);
        a2 = dot2u(v2.z, s2, a2); a2 = dot2u(v2.w, s3, a2);
        a3 = dot2u(v3.x, s0, a3); a3 = dot2u(v3.y, s1, a3);
        a3 = dot2u(v3.z, s2, a3); a3 = dot2u(v3.w, s3, a3);
      }
#pragma unroll
      for (int m = 0; m < MLDS; m++) {          // LDS chunks
        unsigned int s0 = (unsigned int)__builtin_amdgcn_readlane(up, 32 + 4 * m + 0);
        unsigned int s1 = (unsigned int)__builtin_amdgcn_readlane(up, 32 + 4 * m + 1);
        unsigned int s2 = (unsigned int)__builtin_amdgcn_readlane(up, 32 + 4 * m + 2);
        unsigned int s3 = (unsigned int)__builtin_amdgcn_readlane(up, 32 + 4 * m + 3);
        uint4 v0 = Alds[(0 * 4 + m) * 512 + tid];
        uint4 v1 = Alds[(1 * 4 + m) * 512 + tid];
        uint4 v2 = Alds[(2 * 4 + m) * 512 + tid];
        uint4 v3 = Alds[(3 * 4 + m) * 512 + tid];
        a0 = dot2u(v0.x, s0, a0); a0 = dot2u(v0.y, s1, a0);
        a0 = dot2u(v0.z, s2, a0); a0 = dot2u(v0.w, s3, a0);
        a1 = dot2u(v1.x, s0, a1); a1 = dot2u(v1.y, s1, a1);
        a1 = dot2u(v1.z, s2, a1); a1 = dot2u(v1.w, s3, a1);
        a2 = dot2u(v2.x, s0, a2); a2 = dot2u(v2.y, s1, a2);
        a2 = dot2u(v2.z, s2, a2); a2 = dot2u(v2.w, s3, a2);
        a3 = dot2u(v3.x, s0, a3); a3 = dot2u(v3.y, s1, a3);
        a3 = dot2u(v3.z, s2, a3); a3 = dot2u(v3.w, s3, a3);
      }
#pragma unroll
      for (int m = 0; m < MSTR; m++) {          // streamed chunks
        unsigned int s0 = (unsigned int)__builtin_amdgcn_readlane(up, 48 + 4 * m + 0);
        unsigned int s1 = (unsigned int)__builtin_amdgcn_readlane(up, 48 + 4 * m + 1);
        unsigned int s2 = (unsigned int)__builtin_amdgcn_readlane(up, 48 + 4 * m + 2);
        unsigned int s3 = (unsigned int)__builtin_amdgcn_readlane(up, 48 + 4 * m + 3);
        a0 = dot2u(sbuf[0][m].x, s0, a0); a0 = dot2u(sbuf[0][m].y, s1, a0);
        a0 = dot2u(sbuf[0][m].z, s2, a0); a0 = dot2u(sbuf[0][m].w, s3, a0);
        a1 = dot2u(sbuf[1][m].x, s0, a1); a1 = dot2u(sbuf[1][m].y, s1, a1);
        a1 = dot2u(sbuf[1][m].z, s2, a1); a1 = dot2u(sbuf[1][m].w, s3, a1);
        a2 = dot2u(sbuf[2][m].x, s0, a2); a2 = dot2u(sbuf[2][m].y, s1, a2);
        a2 = dot2u(sbuf[2][m].z, s2, a2); a2 = dot2u(sbuf[2][m].w, s3, a2);
        a3 = dot2u(sbuf[3][m].x, s0, a3); a3 = dot2u(sbuf[3][m].y, s1, a3);
        a3 = dot2u(sbuf[3][m].z, s2, a3); a3 = dot2u(sbuf[3][m].w, s3, a3);
      }
      // partials P[kk][256rr + 64r + l] — consecutive lanes, conflict-free
      int pbase = kk * 512 + ((w >> 2) << 8) + l;
      Pf[pbase]       = a0;
      Pf[pbase + 64]  = a1;
      Pf[pbase + 128] = a2;
      Pf[pbase + 192] = a3;
    }
    __syncthreads();   // bar1: partials visible

    // Owner phase: thread tid owns state i = tid.
    {
      int gexpw = 19;
      if (t) {
        const float4* rp = (const float4*)red[cur];
        float4 ra = rp[0], rb = rp[1];
        float sp = ((ra.x + ra.y) + (ra.z + ra.w)) + ((rb.x + rb.y) + (rb.z + rb.w));
        float ls = __log2f(sp);
        int e = ((__builtin_bit_cast(int, sp) >> 23) & 0xff) - 126;  // sp=m*2^e
        c += ls - Dlog;
        Dlog = (float)gexp_prev + ls;
        gexpw = 19 - gexp_prev - e;
      }
      float em = __expf(epre - lse_i);
      float raw;
      if (t) {
        raw = ((Pf[tid] + Pf[512 + tid]) + (Pf[1024 + tid] + Pf[1536 + tid])) * em;
      } else {
        raw = pi_i * em;
      }
      // scaled u (exact pow2); sigma partials for next step
      ((_Float16*)ubuf[cur ^ 1])[tid] = (_Float16)ldexpf(raw, gexpw);
      float s = wave_red_sum(raw);
      if (l == 0) red[cur ^ 1][w] = s;
      gexp_prev = gexpw;
    }
    __syncthreads();   // bar2: u + sigma visible
    cur ^= 1;
  }
  // epilogue: consume last step's sigma
  {
    const float4* rp = (const float4*)red[cur];
    float4 ra = rp[0], rb = rp[1];
    float sp = ((ra.x + ra.y) + (ra.z + ra.w)) + ((rb.x + rb.y) + (rb.z + rb.w));
    c += __log2f(sp) - Dlog;
  }
  if (tid == 0) out[b] = c * 0.69314718055994530942f;
}

extern "C" void kernel_launch(void* const* d_in, const int* in_sizes, int n_in,
                              void* d_out, int out_size, void* d_ws, size_t ws_size,
                              hipStream_t stream) {
  const float* pi = (const float*)d_in[0];
  const float* A  = (const float*)d_in[1];
  const float* E  = (const float*)d_in[2];
  const int*   x  = (const int*)d_in[3];
  const int*   T  = (const int*)d_in[4];
  float* out = (float*)d_out;

  char* ws = (char*)d_ws;
  float*        pi_sm = (float*)(ws + 0);
  float*        lseA  = (float*)(ws + 2048);
  float*        lseE  = (float*)(ws + 4096);
  unsigned int* Apk   = (unsigned int*)(ws + 6144);  // 512*512 fp16 = 512 KB

  hipLaunchKernelGGL(k_pi,      dim3(1),   dim3(512), 0, stream, pi, pi_sm);
  hipLaunchKernelGGL(k_colLse,  dim3(512), dim3(256), 0, stream, A, lseA);
  hipLaunchKernelGGL(k_rowLseE, dim3(512), dim3(256), 0, stream, E, lseE);
  hipLaunchKernelGGL(k_pack,    dim3(256), dim3(512), 0, stream, A, lseA, Apk);
  hipLaunchKernelGGL(k_fwd,     dim3(64),  dim3(512), 0, stream,
                     E, x, T, pi_sm, lseE, (const uint4*)Apk, out);
}

// Round 10
// 1387.484 us; speedup vs baseline: 1.0277x; 1.0277x over previous
//
#include <hip/hip_runtime.h>
#include <math.h>

#define NS   512   // states
#define NO   1024  // observations
#define NB   64    // batch
#define TMAX 512

typedef short bf16x8 __attribute__((ext_vector_type(8)));
typedef float f32x4  __attribute__((ext_vector_type(4)));

__device__ inline float wave_red_sum(float x) {
#pragma unroll
  for (int o = 32; o; o >>= 1) x += __shfl_xor(x, o, 64);
  return x;
}
__device__ inline float wave_red_max(float x) {
#pragma unroll
  for (int o = 32; o; o >>= 1) x = fmaxf(x, __shfl_xor(x, o, 64));
  return x;
}

__device__ inline unsigned short f2bf(float f) {  // round-to-nearest-even
  unsigned int b = __builtin_bit_cast(unsigned int, f);
  b += 0x7FFF + ((b >> 16) & 1);
  return (unsigned short)(b >> 16);
}

#define AGWRITE(dst, src) \
  asm volatile("v_accvgpr_write_b32 %0, %1" : "=a"(dst) : "v"(src))
#define AGREAD(dst, src) \
  asm volatile("v_accvgpr_read_b32 %0, %1" : "=v"(dst) : "a"(src))

// P1: pi softmax -> pi_sm[512]
__global__ void k_pi(const float* __restrict__ pi, float* __restrict__ pi_sm) {
  __shared__ float red[8];
  int tid = threadIdx.x;
  float v = pi[tid];
  float m = wave_red_max(v);
  if ((tid & 63) == 0) red[tid >> 6] = m;
  __syncthreads();
  m = fmaxf(fmaxf(fmaxf(red[0], red[1]), fmaxf(red[2], red[3])),
            fmaxf(fmaxf(red[4], red[5]), fmaxf(red[6], red[7])));
  float e = __expf(v - m);
  float s = wave_red_sum(e);
  __syncthreads();
  if ((tid & 63) == 0) red[tid >> 6] = s;
  __syncthreads();
  s = red[0] + red[1] + red[2] + red[3] + red[4] + red[5] + red[6] + red[7];
  pi_sm[tid] = e / s;
}

// P2: column logsumexp of A (axis 0). One block (256 thr) per column. grid 512.
__global__ void k_colLse(const float* __restrict__ A, float* __restrict__ lseA) {
  __shared__ float redm[4];
  __shared__ float reds[4];
  int k = blockIdx.x, tid = threadIdx.x;
  float a0 = A[tid * NS + k], a1 = A[(tid + 256) * NS + k];
  float m = wave_red_max(fmaxf(a0, a1));
  if ((tid & 63) == 0) redm[tid >> 6] = m;
  __syncthreads();
  m = fmaxf(fmaxf(redm[0], redm[1]), fmaxf(redm[2], redm[3]));
  float s = __expf(a0 - m) + __expf(a1 - m);
  s = wave_red_sum(s);
  if ((tid & 63) == 0) reds[tid >> 6] = s;
  __syncthreads();
  s = reds[0] + reds[1] + reds[2] + reds[3];
  if (tid == 0) lseA[k] = m + __logf(s);
}

// P3: row logsumexp of E (axis 1). One block per row. grid 512 x 256.
__global__ void k_rowLseE(const float* __restrict__ E, float* __restrict__ lseE) {
  __shared__ float red[4];
  int i = blockIdx.x, tid = threadIdx.x;
  const float* row = E + i * NO;
  float a0 = row[tid], a1 = row[tid + 256], a2 = row[tid + 512], a3 = row[tid + 768];
  float m = fmaxf(fmaxf(a0, a1), fmaxf(a2, a3));
  m = wave_red_max(m);
  if ((tid & 63) == 0) red[tid >> 6] = m;
  __syncthreads();
  m = fmaxf(fmaxf(red[0], red[1]), fmaxf(red[2], red[3]));
  float s = __expf(a0 - m) + __expf(a1 - m) + __expf(a2 - m) + __expf(a3 - m);
  s = wave_red_sum(s);
  __syncthreads();
  if ((tid & 63) == 0) red[tid >> 6] = s;
  __syncthreads();
  s = red[0] + red[1] + red[2] + red[3];
  if (tid == 0) lseE[i] = m + __logf(s);
}

// P4: pack A_exp = exp(A - lseA[col]) as bf16 MFMA A-fragments.
// Tile tau = (w*16 + kc)*4 + og covers outs [64w+16og, +16), k [32kc, +32).
// Lane l, element e: A_exp[64w+16og+(l&15)][32kc+8(l>>4)+e]  (e=0..7, 2/word).
// u32 word index W = (tau*64 + l)*4 + h packs e = 2h, 2h+1. grid 256 x 512.
__global__ void k_pack(const float* __restrict__ A, const float* __restrict__ lseA,
                       unsigned int* __restrict__ W) {
  int u = blockIdx.x * 512 + threadIdx.x;   // [0, 131072)
  int h = u & 3;
  int l = (u >> 2) & 63;
  int tau = u >> 8;
  int og = tau & 3;
  int kc = (tau >> 2) & 15;
  int w = tau >> 6;
  int i  = 64 * w + 16 * og + (l & 15);
  int k0 = 32 * kc + 8 * (l >> 4) + 2 * h;
  float e0 = __expf(A[i * NS + k0]     - lseA[k0]);
  float e1 = __expf(A[i * NS + k0 + 1] - lseA[k0 + 1]);
  W[u] = (unsigned int)f2bf(e0) | ((unsigned int)f2bf(e1) << 16);
}

// Main forward: one block (512 thr, 8 waves) per batch; MFMA matvec.
// Wave w owns outs [64w, 64w+64) = 4 out-groups; sweeps 16 k-tiles:
//   kc 0..7  AGPR (AGWRITE prologue; AGREAD->VGPR->MFMA, r5-proven roundtrip)
//   kc 8..11 LDS (128 KB)
//   kc 12..15 streamed from L2 each step (128 KB/CU/step, hoist-blocked)
// u replicated across B's 16 columns -> D cols all equal the matvec.
// NaN fixes vs r8: (1) __align__(16) on vbufS/ubuf -- r8 took b128 LDS
// accesses through 4B/2B-aligned arrays (undefined on CDNA); (2) no direct
// "=a"-asm -> MFMA operand feed (untested regalloc path) -- AGREAD first.
// Deferred pow2 rescale (absmax 0.0 in r3/r4/r5/r7).
__global__ __launch_bounds__(512)
__attribute__((amdgpu_waves_per_eu(2)))
void k_fwd(
    const float* __restrict__ E, const int* __restrict__ x,
    const int* __restrict__ Tlen, const float* __restrict__ pi_sm,
    const float* __restrict__ lseE, const uint4* __restrict__ Apk,
    float* __restrict__ out) {
  __shared__ uint4 AldsT[8 * 4 * 4 * 64];       // 128 KB: tile (w, j, og), lane l
  __shared__ __align__(16) float vbufS[NS];     // 2 KB raw matvec v
  __shared__ __align__(16) unsigned short ubuf[NS];  // 1 KB u (bf16)
  __shared__ int xrow[TMAX];                    // 2 KB
  __shared__ __align__(16) float red[2][8];     // ping-pong sigma partials
  int b = blockIdx.x, tid = threadIdx.x;
  int w = tid >> 6, l = tid & 63;
  int lg = l >> 4;                              // 16-lane group = k-subgroup

  // Prologue: AGPR tiles kc 0..7 (asm-forced residency, r5-proven).
  uint4 aag[4][8];
#pragma unroll
  for (int og = 0; og < 4; og++) {
#pragma unroll
    for (int kc = 0; kc < 8; kc++) {
      uint4 tmp = Apk[((w * 16 + kc) * 4 + og) * 64 + l];
      AGWRITE(aag[og][kc].x, tmp.x);
      AGWRITE(aag[og][kc].y, tmp.y);
      AGWRITE(aag[og][kc].z, tmp.z);
      AGWRITE(aag[og][kc].w, tmp.w);
    }
  }
  // LDS tiles kc 8..11.
#pragma unroll
  for (int j = 0; j < 4; j++)
#pragma unroll
    for (int og = 0; og < 4; og++)
      AldsT[((w * 4 + j) * 4 + og) * 64 + l] = Apk[((w * 16 + 8 + j) * 4 + og) * 64 + l];

  for (int t2 = tid; t2 < TMAX; t2 += 512) xrow[t2] = x[b * TMAX + t2];

  float pi_i  = pi_sm[tid];
  float lse_i = lseE[tid];
  const float* Erow = E + tid * NO;
  int Tb = Tlen[b];
  float c = 0.f;        // log2-domain accumulator
  float Dlog = 0.f;     // log2 d_{t-1}
  int gexp_prev = 19;
  int cur = 0;
  __syncthreads();

  for (int t = 0; t < Tb; t++) {
    float epre = Erow[xrow[t]];     // gather early; hides under MFMA phase
    if (t) {
      // streamed tiles kc 12..15: issue early, opaque index blocks hoisting
      int lo = l;
      asm volatile("" : "+v"(lo));
      uint4 sbuf[4][4];
#pragma unroll
      for (int ks = 0; ks < 4; ks++)
#pragma unroll
        for (int og = 0; og < 4; og++)
          sbuf[og][ks] = Apk[((w * 16 + 12 + ks) * 4 + og) * 64 + lo];

      const uint4* ub = (const uint4*)ubuf;     // B-frags: 16B at kc*64 + lg*16
      f32x4 d0 = {0.f, 0.f, 0.f, 0.f};
      f32x4 d1 = {0.f, 0.f, 0.f, 0.f};
      f32x4 d2 = {0.f, 0.f, 0.f, 0.f};
      f32x4 d3 = {0.f, 0.f, 0.f, 0.f};
#pragma unroll
      for (int kc = 0; kc < 8; kc++) {          // AGPR tiles (via AGREAD)
        bf16x8 bb = __builtin_bit_cast(bf16x8, ub[kc * 4 + lg]);
        uint4 v0, v1, v2, v3;
        AGREAD(v0.x, aag[0][kc].x); AGREAD(v0.y, aag[0][kc].y);
        AGREAD(v0.z, aag[0][kc].z); AGREAD(v0.w, aag[0][kc].w);
        AGREAD(v1.x, aag[1][kc].x); AGREAD(v1.y, aag[1][kc].y);
        AGREAD(v1.z, aag[1][kc].z); AGREAD(v1.w, aag[1][kc].w);
        AGREAD(v2.x, aag[2][kc].x); AGREAD(v2.y, aag[2][kc].y);
        AGREAD(v2.z, aag[2][kc].z); AGREAD(v2.w, aag[2][kc].w);
        AGREAD(v3.x, aag[3][kc].x); AGREAD(v3.y, aag[3][kc].y);
        AGREAD(v3.z, aag[3][kc].z); AGREAD(v3.w, aag[3][kc].w);
        d0 = __builtin_amdgcn_mfma_f32_16x16x32_bf16(
               __builtin_bit_cast(bf16x8, v0), bb, d0, 0, 0, 0);
        d1 = __builtin_amdgcn_mfma_f32_16x16x32_bf16(
               __builtin_bit_cast(bf16x8, v1), bb, d1, 0, 0, 0);
        d2 = __builtin_amdgcn_mfma_f32_16x16x32_bf16(
               __builtin_bit_cast(bf16x8, v2), bb, d2, 0, 0, 0);
        d3 = __builtin_amdgcn_mfma_f32_16x16x32_bf16(
               __builtin_bit_cast(bf16x8, v3), bb, d3, 0, 0, 0);
      }
#pragma unroll
      for (int j = 0; j < 4; j++) {             // LDS tiles kc 8..11
        bf16x8 bb = __builtin_bit_cast(bf16x8, ub[(8 + j) * 4 + lg]);
        uint4 v0 = AldsT[((w * 4 + j) * 4 + 0) * 64 + l];
        uint4 v1 = AldsT[((w * 4 + j) * 4 + 1) * 64 + l];
        uint4 v2 = AldsT[((w * 4 + j) * 4 + 2) * 64 + l];
        uint4 v3 = AldsT[((w * 4 + j) * 4 + 3) * 64 + l];
        d0 = __builtin_amdgcn_mfma_f32_16x16x32_bf16(
               __builtin_bit_cast(bf16x8, v0), bb, d0, 0, 0, 0);
        d1 = __builtin_amdgcn_mfma_f32_16x16x32_bf16(
               __builtin_bit_cast(bf16x8, v1), bb, d1, 0, 0, 0);
        d2 = __builtin_amdgcn_mfma_f32_16x16x32_bf16(
               __builtin_bit_cast(bf16x8, v2), bb, d2, 0, 0, 0);
        d3 = __builtin_amdgcn_mfma_f32_16x16x32_bf16(
               __builtin_bit_cast(bf16x8, v3), bb, d3, 0, 0, 0);
      }
#pragma unroll
      for (int ks = 0; ks < 4; ks++) {          // streamed tiles kc 12..15
        bf16x8 bb = __builtin_bit_cast(bf16x8, ub[(12 + ks) * 4 + lg]);
        d0 = __builtin_amdgcn_mfma_f32_16x16x32_bf16(
               __builtin_bit_cast(bf16x8, sbuf[0][ks]), bb, d0, 0, 0, 0);
        d1 = __builtin_amdgcn_mfma_f32_16x16x32_bf16(
               __builtin_bit_cast(bf16x8, sbuf[1][ks]), bb, d1, 0, 0, 0);
        d2 = __builtin_amdgcn_mfma_f32_16x16x32_bf16(
               __builtin_bit_cast(bf16x8, sbuf[2][ks]), bb, d2, 0, 0, 0);
        d3 = __builtin_amdgcn_mfma_f32_16x16x32_bf16(
               __builtin_bit_cast(bf16x8, sbuf[3][ks]), bb, d3, 0, 0, 0);
      }
      // v-write: D cols replicated; 16-lane-group leaders (l&15==0, col 0)
      // hold rows 4*lg..4*lg+3 in regs 0..3 (m89-verified C/D layout).
      if ((l & 15) == 0) {
        *(f32x4*)&vbufS[w * 64 + 0 * 16 + lg * 4] = d0;
        *(f32x4*)&vbufS[w * 64 + 1 * 16 + lg * 4] = d1;
        *(f32x4*)&vbufS[w * 64 + 2 * 16 + lg * 4] = d2;
        *(f32x4*)&vbufS[w * 64 + 3 * 16 + lg * 4] = d3;
      }
    }
    __syncthreads();   // bar1: v visible

    // Phase 2: thread tid owns state i = tid (softmax bookkeeping on VALU).
    {
      int gexpw = 19;
      if (t) {
        const float4* rp = (const float4*)red[cur];
        float4 ra = rp[0], rb = rp[1];
        float sp = ((ra.x + ra.y) + (ra.z + ra.w)) + ((rb.x + rb.y) + (rb.z + rb.w));
        float ls = __log2f(sp);
        int e = ((__builtin_bit_cast(int, sp) >> 23) & 0xff) - 126;  // sp=m*2^e
        c += ls - Dlog;
        Dlog = (float)gexp_prev + ls;
        gexpw = 19 - gexp_prev - e;
      }
      float em = __expf(epre - lse_i);
      float raw = (t ? vbufS[tid] : pi_i) * em;
      ubuf[tid] = f2bf(ldexpf(raw, gexpw));     // scaled u (exact pow2)
      float s = wave_red_sum(raw);
      if (l == 0) red[cur ^ 1][w] = s;
      gexp_prev = gexpw;
    }
    __syncthreads();   // bar2: u + sigma visible
    cur ^= 1;
  }
  // epilogue: consume last step's sigma
  {
    const float4* rp = (const float4*)red[cur];
    float4 ra = rp[0], rb = rp[1];
    float sp = ((ra.x + ra.y) + (ra.z + ra.w)) + ((rb.x + rb.y) + (rb.z + rb.w));
    c += __log2f(sp) - Dlog;
  }
  if (tid == 0) out[b] = c * 0.69314718055994530942f;
}

extern "C" void kernel_launch(void* const* d_in, const int* in_sizes, int n_in,
                              void* d_out, int out_size, void* d_ws, size_t ws_size,
                              hipStream_t stream) {
  const float* pi = (const float*)d_in[0];
  const float* A  = (const float*)d_in[1];
  const float* E  = (const float*)d_in[2];
  const int*   x  = (const int*)d_in[3];
  const int*   T  = (const int*)d_in[4];
  float* out = (float*)d_out;

  char* ws = (char*)d_ws;
  float*        pi_sm = (float*)(ws + 0);
  float*        lseA  = (float*)(ws + 2048);
  float*        lseE  = (float*)(ws + 4096);
  unsigned int* Apk   = (unsigned int*)(ws + 6144);  // 512*512 bf16 = 512 KB

  hipLaunchKernelGGL(k_pi,      dim3(1),   dim3(512), 0, stream, pi, pi_sm);
  hipLaunchKernelGGL(k_colLse,  dim3(512), dim3(256), 0, stream, A, lseA);
  hipLaunchKernelGGL(k_rowLseE, dim3(512), dim3(256), 0, stream, E, lseE);
  hipLaunchKernelGGL(k_pack,    dim3(256), dim3(512), 0, stream, A, lseA, Apk);
  hipLaunchKernelGGL(k_fwd,     dim3(64),  dim3(512), 0, stream,
                     E, x, T, pi_sm, lseE, (const uint4*)Apk, out);
}

// Round 11
// 919.004 us; speedup vs baseline: 1.5516x; 1.5098x over previous
//
#include <hip/hip_runtime.h>
#include <math.h>

#define NS   512   // states
#define NO   1024  // observations
#define NB   64    // batch
#define TMAX 512

#define QREG 45    // uint4 chunks (8 fp16 k-values each): compiler streams these
#define QLDS 19    // uint4 chunks held in LDS: k 360..511

typedef _Float16 h2v __attribute__((ext_vector_type(2)));

__device__ inline float wave_red_sum(float x) {
#pragma unroll
  for (int o = 32; o; o >>= 1) x += __shfl_xor(x, o, 64);
  return x;
}
__device__ inline float wave_red_max(float x) {
#pragma unroll
  for (int o = 32; o; o >>= 1) x = fmaxf(x, __shfl_xor(x, o, 64));
  return x;
}

__device__ inline float dot2u(unsigned int a, unsigned int b, float c) {
#if __has_builtin(__builtin_amdgcn_fdot2)
  return __builtin_amdgcn_fdot2(__builtin_bit_cast(h2v, a),
                                __builtin_bit_cast(h2v, b), c, false);
#else
  h2v av = __builtin_bit_cast(h2v, a), bv = __builtin_bit_cast(h2v, b);
  return c + (float)av.x * (float)bv.x + (float)av.y * (float)bv.y;
#endif
}

// P1: pi softmax -> pi_sm[512]
__global__ void k_pi(const float* __restrict__ pi, float* __restrict__ pi_sm) {
  __shared__ float red[8];
  int tid = threadIdx.x;
  float v = pi[tid];
  float m = wave_red_max(v);
  if ((tid & 63) == 0) red[tid >> 6] = m;
  __syncthreads();
  m = fmaxf(fmaxf(fmaxf(red[0], red[1]), fmaxf(red[2], red[3])),
            fmaxf(fmaxf(red[4], red[5]), fmaxf(red[6], red[7])));
  float e = __expf(v - m);
  float s = wave_red_sum(e);
  __syncthreads();
  if ((tid & 63) == 0) red[tid >> 6] = s;
  __syncthreads();
  s = red[0] + red[1] + red[2] + red[3] + red[4] + red[5] + red[6] + red[7];
  pi_sm[tid] = e / s;
}

// P2: column logsumexp of A (axis 0). One block (256 thr) per column. grid 512.
__global__ void k_colLse(const float* __restrict__ A, float* __restrict__ lseA) {
  __shared__ float redm[4];
  __shared__ float reds[4];
  int k = blockIdx.x, tid = threadIdx.x;
  float a0 = A[tid * NS + k], a1 = A[(tid + 256) * NS + k];
  float m = wave_red_max(fmaxf(a0, a1));
  if ((tid & 63) == 0) redm[tid >> 6] = m;
  __syncthreads();
  m = fmaxf(fmaxf(redm[0], redm[1]), fmaxf(redm[2], redm[3]));
  float s = __expf(a0 - m) + __expf(a1 - m);
  s = wave_red_sum(s);
  if ((tid & 63) == 0) reds[tid >> 6] = s;
  __syncthreads();
  s = reds[0] + reds[1] + reds[2] + reds[3];
  if (tid == 0) lseA[k] = m + __logf(s);
}

// P3: row logsumexp of E (axis 1). One block per row. grid 512 x 256.
__global__ void k_rowLseE(const float* __restrict__ E, float* __restrict__ lseE) {
  __shared__ float red[4];
  int i = blockIdx.x, tid = threadIdx.x;
  const float* row = E + i * NO;
  float a0 = row[tid], a1 = row[tid + 256], a2 = row[tid + 512], a3 = row[tid + 768];
  float m = fmaxf(fmaxf(a0, a1), fmaxf(a2, a3));
  m = wave_red_max(m);
  if ((tid & 63) == 0) red[tid >> 6] = m;
  __syncthreads();
  m = fmaxf(fmaxf(red[0], red[1]), fmaxf(red[2], red[3]));
  float s = __expf(a0 - m) + __expf(a1 - m) + __expf(a2 - m) + __expf(a3 - m);
  s = wave_red_sum(s);
  __syncthreads();
  if ((tid & 63) == 0) red[tid >> 6] = s;
  __syncthreads();
  s = red[0] + red[1] + red[2] + red[3];
  if (tid == 0) lseE[i] = m + __logf(s);
}

// P4: pack A_exp = exp(A - lseA[col]) fp16, chunk-major:
// uint4 chunk Aall[q*512 + i] = row i, k = 8q..8q+7. Word
// W[(q*512+i)*4 + h] packs k = 8q+2h, 8q+2h+1. grid 256 x 512.
__global__ void k_pack(const float* __restrict__ A, const float* __restrict__ lseA,
                       unsigned int* __restrict__ W) {
  int u = blockIdx.x * 512 + threadIdx.x;   // [0, 64*512*4)
  int q = u >> 11;
  int r = u & 2047;
  int i = r >> 2;
  int h = r & 3;
  int k0 = q * 8 + h * 2;
  float e0 = __expf(A[i * NS + k0]     - lseA[k0]);
  float e1 = __expf(A[i * NS + k0 + 1] - lseA[k0 + 1]);
  h2v p;
  p.x = (_Float16)e0;
  p.y = (_Float16)e1;
  W[u] = __builtin_bit_cast(unsigned int, p);
}

// Main forward: one block (512 thr, 8 waves) per batch; thread tid = state i.
// EXACT r1 structure (measured best, 957us k_fwd): areg loads left to the
// compiler (it sinks them into an L2 stream at ~105 B/cy that overlaps with
// 2-wave TLP; every attempt to force residency -- pin r3, AGPR r5/r7,
// 16-wave r4, MFMA r10 -- measured WORSE). One change vs r1:
// deferred pow2 rescale, ONE barrier/step (numerics absmax 0.0 in
// r3/r4/r5/r7/r10): sigma_t reduced at step t, consumed pre-dot at t+1 so
// the red[] round-trip + log2 bookkeeping hides under the dot.
__global__ __launch_bounds__(512, 1) void k_fwd(
    const float* __restrict__ E, const int* __restrict__ x,
    const int* __restrict__ Tlen, const float* __restrict__ pi_sm,
    const float* __restrict__ lseE, const uint4* __restrict__ Aall,
    float* __restrict__ out) {
  __shared__ uint4 Alds[QLDS * 512];            // 155648 B
  __shared__ uint4 vbuf[2][NS / 8];             // 2 KB ping-pong (fp16 u)
  __shared__ int xrow[TMAX];                    // 2 KB
  __shared__ __align__(16) float red[2][8];     // ping-pong sigma partials
  int b = blockIdx.x, tid = threadIdx.x;

  // A chunks: 45 "register" chunks (compiler will stream) + 19 LDS chunks.
  uint4 areg[QREG];
#pragma unroll
  for (int q = 0; q < QREG; q++) areg[q] = Aall[q * 512 + tid];
#pragma unroll
  for (int q = 0; q < QLDS; q++) Alds[q * 512 + tid] = Aall[(QREG + q) * 512 + tid];

  for (int t = tid; t < TMAX; t += 512) xrow[t] = x[b * TMAX + t];

  float pi_i  = pi_sm[tid];
  float lse_i = lseE[tid];
  const float* Erow = E + tid * NO;
  int Tb = Tlen[b];
  float c = 0.f;        // log2-domain accumulator
  float Dlog = 0.f;     // log2 d_{t-1}
  int gexp_prev = 19;
  int cur = 0;
  __syncthreads();

  for (int t = 0; t < Tb; t++) {
    int nxt = cur ^ 1;
    float epre = Erow[xrow[t]];     // issued early; latency hides under dot
    int gexpw;
    if (t == 0) {
      gexpw = 19;
    } else {
      // consume previous step's sigma (deferred; gates only the u-write)
      const float4* rp = (const float4*)red[cur];
      float4 ra = rp[0], rb = rp[1];
      float sp = ((ra.x + ra.y) + (ra.z + ra.w)) + ((rb.x + rb.y) + (rb.z + rb.w));
      float ls = __log2f(sp);
      int e = ((__builtin_bit_cast(int, sp) >> 23) & 0xff) - 126;  // sp = m*2^e
      c += ls - Dlog;                 // += log2 s_{t-1}
      Dlog = (float)gexp_prev + ls;   // log2 d_{t-1}
      gexpw = 19 - gexp_prev - e;
    }
    float acc;
    if (t == 0) {
      acc = pi_i;
    } else {
      float a0 = 0.f, a1 = 0.f, a2 = 0.f, a3 = 0.f;
      const uint4* vp = vbuf[cur];
#pragma unroll
      for (int q = 0; q < QREG; q++) {
        uint4 vv = vp[q];                      // wave-uniform broadcast
        a0 = dot2u(areg[q].x, vv.x, a0);
        a1 = dot2u(areg[q].y, vv.y, a1);
        a2 = dot2u(areg[q].z, vv.z, a2);
        a3 = dot2u(areg[q].w, vv.w, a3);
      }
#pragma unroll
      for (int q = 0; q < QLDS; q++) {
        uint4 av = Alds[q * 512 + tid];        // private, conflict-free
        uint4 vv = vp[QREG + q];
        a0 = dot2u(av.x, vv.x, a0);
        a1 = dot2u(av.y, vv.y, a1);
        a2 = dot2u(av.z, vv.z, a2);
        a3 = dot2u(av.w, vv.w, a3);
      }
      acc = (a0 + a1) + (a2 + a3);
    }
    float em = __expf(epre - lse_i);
    float raw = acc * em;
    // write scaled u (exact pow2 scale); avg component mid-fp16-range
    ((_Float16*)vbuf[nxt])[tid] = (_Float16)ldexpf(raw, gexpw);
    // reduce raw for next step's sigma
    float s = wave_red_sum(raw);
    if ((tid & 63) == 0) red[nxt][tid >> 6] = s;
    gexp_prev = gexpw;
    cur = nxt;
    __syncthreads();
  }
  // final: consume last step's sigma
  {
    const float4* rp = (const float4*)red[cur];
    float4 ra = rp[0], rb = rp[1];
    float sp = ((ra.x + ra.y) + (ra.z + ra.w)) + ((rb.x + rb.y) + (rb.z + rb.w));
    c += __log2f(sp) - Dlog;
  }
  if (tid == 0) out[b] = c * 0.69314718055994530942f;
}

extern "C" void kernel_launch(void* const* d_in, const int* in_sizes, int n_in,
                              void* d_out, int out_size, void* d_ws, size_t ws_size,
                              hipStream_t stream) {
  const float* pi = (const float*)d_in[0];
  const float* A  = (const float*)d_in[1];
  const float* E  = (const float*)d_in[2];
  const int*   x  = (const int*)d_in[3];
  const int*   T  = (const int*)d_in[4];
  float* out = (float*)d_out;

  char* ws = (char*)d_ws;
  float*        pi_sm = (float*)(ws + 0);
  float*        lseA  = (float*)(ws + 2048);
  float*        lseE  = (float*)(ws + 4096);
  unsigned int* Apk   = (unsigned int*)(ws + 6144);  // 512*512 fp16 = 512 KB

  hipLaunchKernelGGL(k_pi,      dim3(1),   dim3(512), 0, stream, pi, pi_sm);
  hipLaunchKernelGGL(k_colLse,  dim3(512), dim3(256), 0, stream, A, lseA);
  hipLaunchKernelGGL(k_rowLseE, dim3(512), dim3(256), 0, stream, E, lseE);
  hipLaunchKernelGGL(k_pack,    dim3(256), dim3(512), 0, stream, A, lseA, Apk);
  hipLaunchKernelGGL(k_fwd,     dim3(64),  dim3(512), 0, stream,
                     E, x, T, pi_sm, lseE, (const uint4*)Apk, out);
}